// Round 5
// baseline (624.879 us; speedup 1.0000x reference)
//
#include <hip/hip_runtime.h>
#include <hip/hip_bf16.h>

// Performer / FAVOR+ noncausal attention. ALL inputs + output FLOAT32.
// Intermediates bf16/f32. MFMA (16x16x32 bf16) for GEMMs + fused num/den.
// This revision (vs R4): 3-slot ring K-loop with COUNTED vmcnt + raw
// s_barrier (T3+T4). R4 showed 2-phase dbuf w/ __syncthreads is neutral:
// the implicit vmcnt(0) drain at each barrier kills the prefetch. Now
// tiles k,k+1 stay in flight across barriers (vmcnt(4), never 0 in-loop);
// slot(k+2)=slot(k-1) was last read before barrier k => single barrier
// per iter is race-free. Last 2 iters peeled (vmcnt(4)/vmcnt(0)).
#define B_   4
#define L_   4096
#define HID_ 1024
#define H_   16
#define DH_  64
#define M_   128
#define BL_  (B_*L_)        // 16384
#define NROW (BL_*H_)       // 262144

using short8 = __attribute__((ext_vector_type(8))) short;
using f32x4  = __attribute__((ext_vector_type(4))) float;

__device__ __forceinline__ float b2f(ushort s) {
    return __builtin_bit_cast(float, (unsigned int)s << 16);
}
__device__ __forceinline__ ushort f2b(float f) {  // RNE
    unsigned int u = __builtin_bit_cast(unsigned int, f);
    u += 0x7fffu + ((u >> 16) & 1u);
    return (ushort)(u >> 16);
}

// async global->LDS, 16B per lane; LDS dest = wave-uniform base + lane*16
__device__ __forceinline__ void gld16(void* lds, const void* g) {
    __builtin_amdgcn_global_load_lds(
        (const __attribute__((address_space(1))) unsigned int*)g,
        (__attribute__((address_space(3))) unsigned int*)lds, 16, 0, 0);
}

#define VMCNT4 asm volatile("s_waitcnt vmcnt(4)" ::: "memory")
#define VMCNT0 asm volatile("s_waitcnt vmcnt(0)" ::: "memory")
#define SBAR do { __builtin_amdgcn_sched_barrier(0); \
                  __builtin_amdgcn_s_barrier(); \
                  __builtin_amdgcn_sched_barrier(0); } while (0)

// XCD-chunked bijective remap for grid (8,128) = 1024 blocks (1024%8==0).
__device__ __forceinline__ void xcd_swz_8x128(int& bx, int& by) {
    int orig = (int)blockIdx.x + ((int)blockIdx.y << 3);
    int nu = ((orig & 7) << 7) + (orig >> 3);
    bx = nu & 7; by = nu >> 3;
}

// ---------------------------------------------------------------------------
// 128x128-tile MFMA K-loop, 3-slot ring, counted vmcnt, raw s_barrier.
// A[row][k] stride sA, BT[col][k] stride sB (k-contiguous, 16B-aligned).
// As, Bs: 3 x 4096 ushorts (3 x 8KB) each, slot layout [kg(4)][r(128)][8].
// 256 thr / 4 waves; wave w: rows (w>>1)*64.., cols (w&1)*64..; acc[4][4].
// K multiple of 32, K >= 64. Trailing __syncthreads before LDS reuse.
// ---------------------------------------------------------------------------
__device__ __forceinline__ void mfma_gemm_g(
    const ushort* __restrict__ A, const ushort* __restrict__ BT,
    int sA, int sB, int K, ushort* As, ushort* Bs, f32x4 acc[4][4])
{
    const int t = threadIdx.x, w = t >> 6, lane = t & 63;
    const int wm = w >> 1, wn = w & 1, kg = lane >> 4, lr = lane & 15;
    const ushort* a0 = A  + (size_t)lane * sA + w * 8;
    const ushort* a1 = A  + (size_t)(64 + lane) * sA + w * 8;
    const ushort* b0 = BT + (size_t)lane * sB + w * 8;
    const ushort* b1 = BT + (size_t)(64 + lane) * sB + w * 8;
    ushort* lA0 = As + (size_t)(w * 128) * 8;
    ushort* lA1 = As + (size_t)(w * 128 + 64) * 8;
    ushort* lB0 = Bs + (size_t)(w * 128) * 8;
    ushort* lB1 = Bs + (size_t)(w * 128 + 64) * 8;

    auto stg = [&](int slot, int koff) {
        gld16(lA0 + slot * 4096, a0 + koff);
        gld16(lA1 + slot * 4096, a1 + koff);
        gld16(lB0 + slot * 4096, b0 + koff);
        gld16(lB1 + slot * 4096, b1 + koff);
    };
    auto compute = [&](int slot) {
        const ushort* Ac = As + slot * 4096;
        const ushort* Bc = Bs + slot * 4096;
        short8 av[4], bv[4];
        #pragma unroll
        for (int i = 0; i < 4; ++i)
            av[i] = *(const short8*)(Ac + ((size_t)kg*128 + wm*64 + i*16 + lr) * 8);
        #pragma unroll
        for (int i = 0; i < 4; ++i)
            bv[i] = *(const short8*)(Bc + ((size_t)kg*128 + wn*64 + i*16 + lr) * 8);
        #pragma unroll
        for (int mt = 0; mt < 4; ++mt)
            #pragma unroll
            for (int nt = 0; nt < 4; ++nt)
                acc[mt][nt] = __builtin_amdgcn_mfma_f32_16x16x32_bf16(
                    av[mt], bv[nt], acc[mt][nt], 0, 0, 0);
    };

    const int n = K >> 5;                 // K-steps of 32
    stg(0, 0); stg(1, 32);                // prologue: tiles 0,1 in flight
    int s0 = 0, s1 = 1, s2 = 2;
    for (int k = 0; k + 2 < n; ++k) {
        VMCNT4;                           // tile k landed (k+1 in flight)
        SBAR;
        stg(s2, (k + 2) * 32);            // issue tile k+2 (slot = (k-1)%3)
        compute(s0);
        int tmp = s0; s0 = s1; s1 = s2; s2 = tmp;
    }
    VMCNT4; SBAR; compute(s0);            // tile n-2 (n-1 still in flight)
    VMCNT0; SBAR; compute(s1);            // tile n-1
    __syncthreads();                      // LDS safe for reuse by caller
}

// ---------------------------------------------------------------------------
// Fused QK projection + phi (all-MFMA).
// grid (HID/128=8, BL/128=128); block covers heads h0=2*bx, h0+1.
// LDS 48KB: main = As/Bs 3-slot ring; epi = Aq[2][8][128][8] (32KB).
// proj fragments live in registers (proj is 32KB, L1/L2-resident).
// ---------------------------------------------------------------------------
__global__ __launch_bounds__(256) void gemm_phi_mfma(
    const ushort* __restrict__ A, const ushort* __restrict__ BT,
    const float* __restrict__ proj, ushort* __restrict__ OUT)
{
    __shared__ __align__(16) ushort uni[24576];  // 48KB
    const int t = threadIdx.x;

    int bx, by; xcd_swz_8x128(bx, by);
    const int bm = by * 128, bn = bx * 128, h0 = bx * 2;
    f32x4 acc[4][4];
    const f32x4 z4 = {0.f, 0.f, 0.f, 0.f};
    #pragma unroll
    for (int mt = 0; mt < 4; ++mt)
        #pragma unroll
        for (int nt = 0; nt < 4; ++nt) acc[mt][nt] = z4;

    mfma_gemm_g(A + (size_t)bm * HID_, BT + (size_t)bn * HID_,
                HID_, HID_, HID_, uni, uni + 12288, acc);

    const int w = t >> 6, lane = t & 63, wm = w >> 1, wn = w & 1;
    const int lr = lane & 15, rq = lane >> 4;

    // write BOTH heads' q -> Aq[head=wn][kg][row][8]; acc dies here.
    #pragma unroll
    for (int mt = 0; mt < 4; ++mt)
        #pragma unroll
        for (int nt = 0; nt < 4; ++nt)
            #pragma unroll
            for (int p = 0; p < 4; ++p) {
                int row = wm * 64 + mt * 16 + rq * 4 + p;
                int d   = nt * 16 + lr;
                uni[(((size_t)wn * 8 + (d >> 3)) * 128 + row) * 8 + (d & 7)]
                    = f2b(acc[mt][nt][p]);
            }

    // proj fragments -> regs: pb[ks][i] = proj[m=wn*64+i*16+lr][(ks*4+rq)*8..+8]
    short8 pb[2][4];
    #pragma unroll
    for (int ks = 0; ks < 2; ++ks)
        #pragma unroll
        for (int i = 0; i < 4; ++i) {
            const float* p = proj + (size_t)(wn*64 + i*16 + lr) * DH_ + (ks*4 + rq) * 8;
            float4 x = *(const float4*)p, y = *(const float4*)(p + 4);
            short8 v;
            v[0]=(short)f2b(x.x); v[1]=(short)f2b(x.y);
            v[2]=(short)f2b(x.z); v[3]=(short)f2b(x.w);
            v[4]=(short)f2b(y.x); v[5]=(short)f2b(y.y);
            v[6]=(short)f2b(y.z); v[7]=(short)f2b(y.w);
            pb[ks][i] = v;
        }
    __syncthreads();

    const float ratio = 0.08838834764831845f;
    #pragma unroll
    for (int hs = 0; hs < 2; ++hs) {
        f32x4 a2[4][4];
        #pragma unroll
        for (int mt = 0; mt < 4; ++mt)
            #pragma unroll
            for (int nt = 0; nt < 4; ++nt) a2[mt][nt] = z4;
        #pragma unroll
        for (int ks = 0; ks < 2; ++ks) {
            short8 av[4];
            #pragma unroll
            for (int i = 0; i < 4; ++i)
                av[i] = *(const short8*)(uni +
                    (((size_t)hs*8 + ks*4 + rq) * 128 + wm*64 + i*16 + lr) * 8);
            #pragma unroll
            for (int mt = 0; mt < 4; ++mt)
                #pragma unroll
                for (int nt = 0; nt < 4; ++nt)
                    a2[mt][nt] = __builtin_amdgcn_mfma_f32_16x16x32_bf16(
                        av[mt], pb[ks][nt], a2[mt][nt], 0, 0, 0);
        }
        #pragma unroll
        for (int mt = 0; mt < 4; ++mt)
            #pragma unroll
            for (int nt = 0; nt < 4; ++nt)
                #pragma unroll
                for (int p = 0; p < 4; ++p) {
                    size_t rowg = bm + wm*64 + mt*16 + rq*4 + p;
                    int m = wn*64 + nt*16 + lr;
                    float v = fmaxf(a2[mt][nt][p] * ratio, 0.f) + 1e-3f;
                    OUT[(rowg * H_ + (h0 + hs)) * M_ + m] = f2b(v);
                }
    }
}

// ---------------------------------------------------------------------------
// Plain MFMA GEMM, bf16 out (V projection)
// ---------------------------------------------------------------------------
__global__ __launch_bounds__(256) void gemm_mfma_bf16(
    const ushort* __restrict__ A, const ushort* __restrict__ BT,
    ushort* __restrict__ C)
{
    __shared__ __align__(16) ushort As[12288], Bs[12288];
    int bx, by; xcd_swz_8x128(bx, by);
    const int bm = by * 128, bn = bx * 128;
    f32x4 acc[4][4];
    const f32x4 z4 = {0.f, 0.f, 0.f, 0.f};
    #pragma unroll
    for (int mt = 0; mt < 4; ++mt)
        #pragma unroll
        for (int nt = 0; nt < 4; ++nt) acc[mt][nt] = z4;
    mfma_gemm_g(A + (size_t)bm * HID_, BT + (size_t)bn * HID_,
                HID_, HID_, HID_, As, Bs, acc);
    const int t = threadIdx.x, w = t >> 6, lane = t & 63;
    const int wm = w >> 1, wn = w & 1, lr = lane & 15, rq = lane >> 4;
    #pragma unroll
    for (int mt = 0; mt < 4; ++mt)
        #pragma unroll
        for (int nt = 0; nt < 4; ++nt)
            #pragma unroll
            for (int p = 0; p < 4; ++p) {
                size_t row = bm + wm*64 + mt*16 + rq*4 + p;
                int col = bn + wn*64 + nt*16 + lr;
                C[row * HID_ + col] = f2b(acc[mt][nt][p]);
            }
}

// ---------------------------------------------------------------------------
// Plain MFMA GEMM, f32 out (output projection)
// ---------------------------------------------------------------------------
__global__ __launch_bounds__(256) void gemm_mfma_f32(
    const ushort* __restrict__ A, const ushort* __restrict__ BT,
    float* __restrict__ C)
{
    __shared__ __align__(16) ushort As[12288], Bs[12288];
    int bx, by; xcd_swz_8x128(bx, by);
    const int bm = by * 128, bn = bx * 128;
    f32x4 acc[4][4];
    const f32x4 z4 = {0.f, 0.f, 0.f, 0.f};
    #pragma unroll
    for (int mt = 0; mt < 4; ++mt)
        #pragma unroll
        for (int nt = 0; nt < 4; ++nt) acc[mt][nt] = z4;
    mfma_gemm_g(A + (size_t)bm * HID_, BT + (size_t)bn * HID_,
                HID_, HID_, HID_, As, Bs, acc);
    const int t = threadIdx.x, w = t >> 6, lane = t & 63;
    const int wm = w >> 1, wn = w & 1, lr = lane & 15, rq = lane >> 4;
    #pragma unroll
    for (int mt = 0; mt < 4; ++mt)
        #pragma unroll
        for (int nt = 0; nt < 4; ++nt)
            #pragma unroll
            for (int p = 0; p < 4; ++p) {
                size_t row = bm + wm*64 + mt*16 + rq*4 + p;
                int col = bn + wn*64 + nt*16 + lr;
                C[row * HID_ + col] = acc[mt][nt][p];
            }
}

// ---------------------------------------------------------------------------
// f32 -> bf16 elementwise convert (X inputs)
// ---------------------------------------------------------------------------
__global__ __launch_bounds__(256) void cvt_bf16(
    const float* __restrict__ X, ushort* __restrict__ Y, int n4)
{
    for (int i = blockIdx.x * 256 + threadIdx.x; i < n4; i += gridDim.x * 256) {
        float4 v = ((const float4*)X)[i];
        ushort4 o;
        o.x = f2b(v.x); o.y = f2b(v.y); o.z = f2b(v.z); o.w = f2b(v.w);
        ((ushort4*)Y)[i] = o;
    }
}

// ---------------------------------------------------------------------------
// W[k][n] f32 -> WT[n][k] bf16 (1024x1024), 64x64 tiles
// ---------------------------------------------------------------------------
__global__ __launch_bounds__(256) void wtrans(
    const float* __restrict__ W, ushort* __restrict__ WT)
{
    __shared__ float tile[64][65];
    const int k0 = blockIdx.y * 64, n0 = blockIdx.x * 64;
    const int t = threadIdx.x;
    for (int i = t; i < 1024; i += 256) {
        int r = i >> 4, c4 = i & 15;
        float4 v = *(const float4*)(W + (size_t)(k0 + r) * HID_ + n0 + c4 * 4);
        tile[r][c4*4+0] = v.x; tile[r][c4*4+1] = v.y;
        tile[r][c4*4+2] = v.z; tile[r][c4*4+3] = v.w;
    }
    __syncthreads();
    for (int i = t; i < 1024; i += 256) {
        int n = i >> 4, c4 = i & 15;
        ushort4 o;
        o.x = f2b(tile[c4*4+0][n]); o.y = f2b(tile[c4*4+1][n]);
        o.z = f2b(tile[c4*4+2][n]); o.w = f2b(tile[c4*4+3][n]);
        *(ushort4*)(WT + (size_t)(n0 + n) * HID_ + k0 + c4 * 4) = o;
    }
}

// ---------------------------------------------------------------------------
// KP [l][h][m] -> KPt[bh][m][l] bf16, 128x128 tiles, + per-m column sums
// (ksp[bh][lc][m], f32). XOR block swizzle pb = mq ^ (l>>3).
// grid (bh=64, lc=32).
// ---------------------------------------------------------------------------
__global__ __launch_bounds__(256) void kptrans_kernel(
    const ushort* __restrict__ KP, ushort* __restrict__ KPt,
    float* __restrict__ ksp)
{
    __shared__ __align__(16) ushort tile[128*128];   // 32KB, swizzled blocks
    const int bh = blockIdx.x, lc = blockIdx.y;
    const int b = bh >> 4, h = bh & 15;
    const int t = threadIdx.x;
    const size_t src = ((size_t)(b*L_ + lc*128) * H_ + h) * M_;

    #pragma unroll
    for (int it = 0; it < 8; ++it) {                 // load [l][m] swizzled
        int i = it*256 + t;
        int l = i >> 4, mq = i & 15;
        int pb = mq ^ (l >> 3);
        *(uint4*)&tile[l*128 + pb*8] =
            *(const uint4*)&KP[src + (size_t)l*(H_*M_) + mq*8];
    }
    __syncthreads();

    if (t < 128) {                                   // per-m partial sums
        float s = 0.f;
        for (int l = 0; l < 128; ++l) {
            int pb = (t >> 3) ^ (l >> 3);
            s += b2f(tile[l*128 + pb*8 + (t & 7)]);
        }
        ksp[((size_t)bh*32 + lc)*128 + t] = s;
    }

    #pragma unroll
    for (int it = 0; it < 8; ++it) {                 // transposed write-out
        int i = it*256 + t;
        int m = i >> 4, lq = i & 15;
        short8 v;
        #pragma unroll
        for (int j = 0; j < 8; ++j) {
            int l = lq*8 + j;
            int pb = (m >> 3) ^ lq;                  // l>>3 == lq (j<8)
            v[j] = (short)tile[l*128 + pb*8 + (m & 7)];
        }
        *(short8*)&KPt[((size_t)bh*128 + m)*L_ + lc*128 + lq*8] = v;
    }
}

// ---------------------------------------------------------------------------
// V [l][h][d] -> Vt[bh][d][l] bf16, 128x64 tiles. grid (bh=64, lc=32).
// ---------------------------------------------------------------------------
__global__ __launch_bounds__(256) void vtrans_kernel(
    const ushort* __restrict__ V, ushort* __restrict__ Vt)
{
    __shared__ __align__(16) ushort tile[128*64];    // 16KB, swizzled blocks
    const int bh = blockIdx.x, lc = blockIdx.y;
    const int b = bh >> 4, h = bh & 15;
    const int t = threadIdx.x;
    const size_t src = ((size_t)(b*L_ + lc*128) * H_ + h) * DH_;

    #pragma unroll
    for (int it = 0; it < 4; ++it) {                 // load [l][d] swizzled
        int i = it*256 + t;
        int l = i >> 3, mq = i & 7;
        int pb = mq ^ ((l >> 3) & 7);
        *(uint4*)&tile[l*64 + pb*8] =
            *(const uint4*)&V[src + (size_t)l*(H_*DH_) + mq*8];
    }
    __syncthreads();

    #pragma unroll
    for (int it = 0; it < 4; ++it) {                 // transposed write-out
        int i = it*256 + t;
        int d = i >> 4, lq = i & 15;
        short8 v;
        #pragma unroll
        for (int j = 0; j < 8; ++j) {
            int l = lq*8 + j;
            int pb = (d >> 3) ^ (lq & 7);
            v[j] = (short)tile[l*64 + pb*8 + (d & 7)];
        }
        *(short8*)&Vt[((size_t)bh*64 + d)*L_ + lc*128 + lq*8] = v;
    }
}

// ---------------------------------------------------------------------------
// kvs via MFMA, 2-phase dbuf: per (bh, part), C[d(64)][m(128)] over 512 l.
// A=Vt (64 rows), BT=KPt (128 rows), K=512, k-contig.
// Partials KVSP[part][bh][d][m] f32. grid (bh=64, part=8).
// ---------------------------------------------------------------------------
__global__ __launch_bounds__(256) void kvs_mfma(
    const ushort* __restrict__ Vt, const ushort* __restrict__ KPt,
    float* __restrict__ KVSP)
{
    __shared__ __align__(16) ushort As[4096], Bs[8192];  // 2x4KB, 2x8KB
    const int bh = blockIdx.x, part = blockIdx.y;
    const ushort* A  = Vt  + (size_t)bh * 64  * L_ + part * 512;
    const ushort* BT = KPt + (size_t)bh * 128 * L_ + part * 512;
    const int t = threadIdx.x, w = t >> 6, lane = t & 63;
    const int wm = w >> 1, wn = w & 1, kg = lane >> 4, lr = lane & 15;
    const ushort* a0 = A  + (size_t)lane * L_ + w * 8;
    const ushort* b0 = BT + (size_t)lane * L_ + w * 8;
    const ushort* b1 = BT + (size_t)(64 + lane) * L_ + w * 8;
    ushort* lA0 = As + (size_t)(w * 64) * 8;
    ushort* lB0 = Bs + (size_t)(w * 128) * 8;
    ushort* lB1 = Bs + (size_t)(w * 128 + 64) * 8;

    f32x4 acc[2][4];
    const f32x4 z4 = {0.f, 0.f, 0.f, 0.f};
    #pragma unroll
    for (int mt = 0; mt < 2; ++mt)
        #pragma unroll
        for (int nt = 0; nt < 4; ++nt) acc[mt][nt] = z4;

    gld16(lA0, a0); gld16(lB0, b0); gld16(lB1, b1);
    __syncthreads();

    int cur = 0;
    for (int k0 = 0; k0 < 512; k0 += 32) {
        const int nxt = cur ^ 1;
        if (k0 + 32 < 512) {
            gld16(lA0 + nxt * 2048, a0 + k0 + 32);
            gld16(lB0 + nxt * 4096, b0 + k0 + 32);
            gld16(lB1 + nxt * 4096, b1 + k0 + 32);
        }
        const ushort* Ac = As + cur * 2048;
        const ushort* Bc = Bs + cur * 4096;
        short8 av[2], bv[4];
        #pragma unroll
        for (int i = 0; i < 2; ++i)
            av[i] = *(const short8*)(Ac + ((size_t)kg*64 + wm*32 + i*16 + lr) * 8);
        #pragma unroll
        for (int i = 0; i < 4; ++i)
            bv[i] = *(const short8*)(Bc + ((size_t)kg*128 + wn*64 + i*16 + lr) * 8);
        #pragma unroll
        for (int mt = 0; mt < 2; ++mt)
            #pragma unroll
            for (int nt = 0; nt < 4; ++nt)
                acc[mt][nt] = __builtin_amdgcn_mfma_f32_16x16x32_bf16(
                    av[mt], bv[nt], acc[mt][nt], 0, 0, 0);
        __syncthreads();
        cur = nxt;
    }

    const int rq = lane >> 4;
    #pragma unroll
    for (int mt = 0; mt < 2; ++mt)
        #pragma unroll
        for (int nt = 0; nt < 4; ++nt)
            #pragma unroll
            for (int p = 0; p < 4; ++p) {
                int row = wm*32 + mt*16 + rq*4 + p;        // d
                int col = wn*64 + nt*16 + lr;              // m
                KVSP[(((size_t)part*64 + bh)*64 + row)*128 + col]
                    = acc[mt][nt][p];
            }
}

// ---------------------------------------------------------------------------
// kvs_reduce: sum 8 KVS partials + 32 ksp partials -> bf16
// KVSt[bh][d][m] (d<64) = kvs; [64][m] = ks_sum; [65..127][m] = 0
// ---------------------------------------------------------------------------
__global__ __launch_bounds__(256) void kvs_reduce_kernel(
    const float* __restrict__ KVSP, const float* __restrict__ ksp,
    ushort* __restrict__ KVSt)
{
    const int bh = blockIdx.x;
    for (int i = threadIdx.x; i < 128*128; i += 256) {
        int d = i >> 7, m = i & 127;
        ushort v = 0;
        if (d < 64) {
            float s = 0.f;
            #pragma unroll
            for (int p = 0; p < 8; ++p)
                s += KVSP[(((size_t)p*64 + bh)*64 + d)*128 + m];
            v = f2b(s);
        } else if (d == 64) {
            float s = 0.f;
            #pragma unroll
            for (int c = 0; c < 32; ++c)
                s += ksp[((size_t)bh*32 + c)*128 + m];
            v = f2b(s);
        }
        KVSt[(size_t)bh * 16384 + i] = v;
    }
}

// ---------------------------------------------------------------------------
// numden: per (b,h), 128-row tile: [QP rows, K=128 m] x KVSt[128][128].
// Output cols 0..63 = num, col 64 = den -> ATT = num/den (bf16) directly.
// grid (bh=64, L/128=32).
// ---------------------------------------------------------------------------
__global__ __launch_bounds__(256) void numden_mfma(
    const ushort* __restrict__ QP, const ushort* __restrict__ KVSt,
    ushort* __restrict__ ATT)
{
    __shared__ __align__(16) ushort As[12288], Bs[12288];
    __shared__ float sden[128];
    const int bh = blockIdx.x, b = bh >> 4, h = bh & 15;
    const int l0 = blockIdx.y * 128;
    const ushort* Abase = QP + ((size_t)(b * L_ + l0) * H_ + h) * M_;
    const ushort* Bbase = KVSt + (size_t)bh * 16384;

    f32x4 acc[4][4];
    const f32x4 z4 = {0.f, 0.f, 0.f, 0.f};
    #pragma unroll
    for (int mt = 0; mt < 4; ++mt)
        #pragma unroll
        for (int nt = 0; nt < 4; ++nt) acc[mt][nt] = z4;

    mfma_gemm_g(Abase, Bbase, H_*M_, 128, 128, As, Bs, acc);

    const int t = threadIdx.x, w = t >> 6, lane = t & 63;
    const int wm = w >> 1, wn = w & 1, lr = lane & 15, rq = lane >> 4;

    if (wn == 1 && lr == 0) {       // col 64 = den
        #pragma unroll
        for (int mt = 0; mt < 4; ++mt)
            #pragma unroll
            for (int p = 0; p < 4; ++p)
                sden[wm*64 + mt*16 + rq*4 + p] = acc[mt][0][p];
    }
    __syncthreads();

    if (wn == 0) {
        #pragma unroll
        for (int mt = 0; mt < 4; ++mt) {
            #pragma unroll
            for (int p = 0; p < 4; ++p) {
                int row = wm*64 + mt*16 + rq*4 + p;
                float den = fmaxf(sden[row], 1e-10f);
                float rden = 1.0f / den;
                size_t gbase = (size_t)(b * L_ + l0 + row) * HID_ + h * DH_;
                #pragma unroll
                for (int nt = 0; nt < 4; ++nt)
                    ATT[gbase + nt*16 + lr] = f2b(acc[mt][nt][p] * rden);
            }
        }
    }
}

// ---------------------------------------------------------------------------
extern "C" void kernel_launch(void* const* d_in, const int* in_sizes, int n_in,
                              void* d_out, int out_size, void* d_ws, size_t ws_size,
                              hipStream_t stream)
{
    const float* Xq = (const float*)d_in[0];
    const float* Xs = (const float*)d_in[1];
    const float* Wq = (const float*)d_in[2];
    const float* Wk = (const float*)d_in[3];
    const float* Wv = (const float*)d_in[4];
    const float* Wo = (const float*)d_in[5];
    const float* Pj = (const float*)d_in[6];
    float* out = (float*)d_out;

    // Workspace layout (MB-aligned, audited disjoint per stage / safe alias):
    //   WqT..WoT [0,8)  Xqb [8,40)  Xsb [40,72)  QPb [72,136)
    //   KPb [136,200)   Vb [200,232)
    //   KPt  [8,72)    alias Xqb+Xsb  (dead after gemms)
    //   Vt   [136,168) alias KPb-lo   (KPb dead after kptrans)
    //   KVSP [168,184) alias KPb-mid
    //   KVSt [184,186) alias KPb-hi
    //   ksp  [0,1)     alias WqT      (dead after Q-gemm)
    //   ATT  [200,232) alias Vb       (dead after vtrans)
    char* ws = (char*)d_ws;
    ushort* WqT = (ushort*)(ws + 0);
    ushort* WkT = (ushort*)(ws + 2097152);
    ushort* WvT = (ushort*)(ws + 4194304);
    ushort* WoT = (ushort*)(ws + 6291456);
    ushort* Xqb = (ushort*)(ws + 8388608);
    ushort* Xsb = (ushort*)(ws + 41943040);
    ushort* QPb = (ushort*)(ws + 75497472);
    ushort* KPb = (ushort*)(ws + 142606336);
    ushort* Vb  = (ushort*)(ws + 209715200);
    ushort* KPt = (ushort*)(ws + 8388608);        // 64MB
    ushort* Vt  = (ushort*)(ws + 142606336);      // 32MB
    float*  KVSP = (float*)(ws + 176160768);      // 16MB
    ushort* KVSt = (ushort*)(ws + 192937984);     // 2MB
    float*  ksp  = (float*)(ws + 0);              // 1MB
    ushort* ATT  = Vb;

    dim3 tb(256);

    cvt_bf16<<<4096, tb, 0, stream>>>(Xq, Xqb, BL_*HID_/4);
    cvt_bf16<<<4096, tb, 0, stream>>>(Xs, Xsb, BL_*HID_/4);
    wtrans<<<dim3(16,16), tb, 0, stream>>>(Wq, WqT);
    wtrans<<<dim3(16,16), tb, 0, stream>>>(Wk, WkT);
    wtrans<<<dim3(16,16), tb, 0, stream>>>(Wv, WvT);
    wtrans<<<dim3(16,16), tb, 0, stream>>>(Wo, WoT);

    gemm_phi_mfma<<<dim3(8, 128), tb, 0, stream>>>(Xqb, WqT, Pj, QPb);
    gemm_phi_mfma<<<dim3(8, 128), tb, 0, stream>>>(Xsb, WkT, Pj, KPb);
    gemm_mfma_bf16<<<dim3(8, 128), tb, 0, stream>>>(Xsb, WvT, Vb);

    kptrans_kernel<<<dim3(64, 32), tb, 0, stream>>>(KPb, KPt, ksp);
    vtrans_kernel<<<dim3(64, 32), tb, 0, stream>>>(Vb, Vt);

    kvs_mfma<<<dim3(64, 8), tb, 0, stream>>>(Vt, KPt, KVSP);
    kvs_reduce_kernel<<<64, tb, 0, stream>>>(KVSP, ksp, KVSt);

    numden_mfma<<<dim3(B_*H_, L_/128), tb, 0, stream>>>(QPb, KVSt, ATT);

    gemm_mfma_f32<<<dim3(8, 128), tb, 0, stream>>>(ATT, WoT, out);
    (void)in_sizes; (void)n_in; (void)out_size; (void)ws_size;
}

// Round 6
// 511.712 us; speedup vs baseline: 1.2212x; 1.2212x over previous
//
#include <hip/hip_runtime.h>
#include <hip/hip_bf16.h>

// Performer / FAVOR+ noncausal attention. ALL inputs + output FLOAT32.
// Intermediates bf16/f32. MFMA (16x16x32 bf16) for GEMMs + fused num/den.
// This revision (vs R5): the four big GEMMs (QK-phi x2, V-proj, out-proj)
// move to a 256x256-tile 8-wave phase-interleaved core (BK=64, 128KB LDS
// double-buffer). R2-R5 showed the 128^2 4-wave structure is pinned at
// ~380 TF by staging intensity (65 FLOP/B vs ~61 FLOP/B L2 break-even);
// 256^2 doubles intensity to 128 FLOP/B. Schedule: per K-tile 4 quadrant
// phases (8 ds_read_b128 + 16 MFMA each, setprio-wrapped), next-tile A/B
// stages issued mid-compute, one __syncthreads per K-tile. numden/kvs/
// transposes/cvt stay at the R4-verified versions.
#define B_   4
#define L_   4096
#define HID_ 1024
#define H_   16
#define DH_  64
#define M_   128
#define BL_  (B_*L_)        // 16384
#define NROW (BL_*H_)       // 262144

using short8 = __attribute__((ext_vector_type(8))) short;
using f32x4  = __attribute__((ext_vector_type(4))) float;

__device__ __forceinline__ float b2f(ushort s) {
    return __builtin_bit_cast(float, (unsigned int)s << 16);
}
__device__ __forceinline__ ushort f2b(float f) {  // RNE
    unsigned int u = __builtin_bit_cast(unsigned int, f);
    u += 0x7fffu + ((u >> 16) & 1u);
    return (ushort)(u >> 16);
}

// async global->LDS, 16B per lane; LDS dest = wave-uniform base + lane*16
__device__ __forceinline__ void gld16(void* lds, const void* g) {
    __builtin_amdgcn_global_load_lds(
        (const __attribute__((address_space(1))) unsigned int*)g,
        (__attribute__((address_space(3))) unsigned int*)lds, 16, 0, 0);
}

// XCD-chunked bijective remap, grid (4,64) = 256 blocks (256%8==0):
// XCD x owns by in [x*8, x*8+8), all 4 bx -> A-panel L2 locality.
__device__ __forceinline__ void xcd_swz_4x64(int& bx, int& by) {
    int orig = (int)blockIdx.x + ((int)blockIdx.y << 2);
    int nu = ((orig & 7) << 5) + (orig >> 3);
    bx = nu & 3; by = nu >> 2;
}

// XCD-chunked bijective remap for grid (8,128) = 1024 blocks.
__device__ __forceinline__ void xcd_swz_8x128(int& bx, int& by) {
    int orig = (int)blockIdx.x + ((int)blockIdx.y << 3);
    int nu = ((orig & 7) << 7) + (orig >> 3);
    bx = nu & 7; by = nu >> 3;
}

// ---------------------------------------------------------------------------
// 256x256-tile 8-wave MFMA core, K=1024 fixed (16 K-tiles of BK=64).
// A[row][k] stride sA, BT[col][k] stride sB (k-contiguous, 16B-aligned).
// LA, LB: 2 bufs x 16384 ushorts each ([kq(8)][r(256)][8] per buf, 32KB).
// 512 thr / 8 waves (2M x 4N); wave (wm,wn): rows wm*128.., cols wn*64..;
// acc[8][4] (f32x4). Per K-tile: 4 quadrant phases (kk=q>>1, mh=q&1),
// each 8 ds_read_b128 + 16 MFMA; stage(kt+1) A after q0, B after q1;
// one __syncthreads per K-tile (drains loads issued 2-3 phases earlier).
// ---------------------------------------------------------------------------
__device__ __forceinline__ void gemm256_core(
    const ushort* __restrict__ A, const ushort* __restrict__ BT,
    int sA, int sB, ushort* LA, ushort* LB, f32x4 acc[8][4])
{
    const int t = threadIdx.x, w = t >> 6, lane = t & 63;
    const int wm = w >> 2, wn = w & 3, kg = lane >> 4, lr = lane & 15;
    const ushort* ga = A  + (size_t)lane * sA + w * 8;   // wave w stages kq=w
    const ushort* gb = BT + (size_t)lane * sB + w * 8;
    ushort* la = LA + (size_t)(w * 256) * 8;
    ushort* lb = LB + (size_t)(w * 256) * 8;

    auto stageA = [&](int buf, int kt) {
        const ushort* g = ga + kt * 64;
        ushort* l = la + buf * 16384;
        #pragma unroll
        for (int j = 0; j < 4; ++j)
            gld16(l + (size_t)j * 512, g + (size_t)j * 64 * sA);
    };
    auto stageB = [&](int buf, int kt) {
        const ushort* g = gb + kt * 64;
        ushort* l = lb + buf * 16384;
        #pragma unroll
        for (int j = 0; j < 4; ++j)
            gld16(l + (size_t)j * 512, g + (size_t)j * 64 * sB);
    };
    auto compute = [&](int buf, int q) {
        const int kk = q >> 1, mh = q & 1;
        const ushort* lA_ = LA + buf * 16384;
        const ushort* lB_ = LB + buf * 16384;
        short8 av[4], bv[4];
        #pragma unroll
        for (int i = 0; i < 4; ++i)
            av[i] = *(const short8*)(lA_ +
                ((size_t)(kk*4 + kg)*256 + wm*128 + mh*64 + i*16 + lr) * 8);
        #pragma unroll
        for (int i = 0; i < 4; ++i)
            bv[i] = *(const short8*)(lB_ +
                ((size_t)(kk*4 + kg)*256 + wn*64 + i*16 + lr) * 8);
        __builtin_amdgcn_s_setprio(1);
        #pragma unroll
        for (int i = 0; i < 4; ++i)
            #pragma unroll
            for (int j = 0; j < 4; ++j)
                acc[mh*4 + i][j] = __builtin_amdgcn_mfma_f32_16x16x32_bf16(
                    av[i], bv[j], acc[mh*4 + i][j], 0, 0, 0);
        __builtin_amdgcn_s_setprio(0);
    };

    stageA(0, 0); stageB(0, 0);
    for (int kt = 0; kt < 16; ++kt) {
        const int buf = kt & 1;
        __syncthreads();            // tile kt landed (all waves); prev reads done
        compute(buf, 0);
        if (kt < 15) stageA(buf ^ 1, kt + 1);
        compute(buf, 1);
        if (kt < 15) stageB(buf ^ 1, kt + 1);
        compute(buf, 2);
        compute(buf, 3);
    }
    __syncthreads();                // LDS safe for caller reuse
}

__device__ __forceinline__ void zero84(f32x4 acc[8][4]) {
    const f32x4 z4 = {0.f, 0.f, 0.f, 0.f};
    #pragma unroll
    for (int i = 0; i < 8; ++i)
        #pragma unroll
        for (int j = 0; j < 4; ++j) acc[i][j] = z4;
}

// ---------------------------------------------------------------------------
// Fused QK projection + phi, 256^2 core. grid (HID/256=4, BL/256=64), 512thr.
// Block covers heads h0=4*bx .. +3. After the main GEMM all 4 heads' q are
// written to the dead 128KB LDS in A-operand layout (acc dies early), then
// per-head phi: [256 x 64] x projT -> [256 x 128]. proj frags in registers.
// ---------------------------------------------------------------------------
__global__ __launch_bounds__(512) void gemm_phi_mfma256(
    const ushort* __restrict__ A, const ushort* __restrict__ BT,
    const float* __restrict__ proj, ushort* __restrict__ OUT)
{
    __shared__ __align__(16) ushort lds[65536];  // 128KB
    int bx, by; xcd_swz_4x64(bx, by);
    const int bm = by * 256, bn = bx * 256, h0 = bx * 4;

    f32x4 acc[8][4];
    zero84(acc);
    gemm256_core(A + (size_t)bm * HID_, BT + (size_t)bn * HID_,
                 HID_, HID_, lds, lds + 32768, acc);

    const int t = threadIdx.x, w = t >> 6, lane = t & 63;
    const int wm = w >> 2, wn = w & 3, lr = lane & 15, rq = lane >> 4;

    // proj fragments (head-independent): m = wn*32 + n2*16 + lr, k-chunk
    short8 pbv[2][2];
    #pragma unroll
    for (int kk = 0; kk < 2; ++kk)
        #pragma unroll
        for (int n2 = 0; n2 < 2; ++n2) {
            const float* p = proj + (size_t)(wn*32 + n2*16 + lr) * DH_
                                  + (kk*4 + rq) * 8;
            float4 x = *(const float4*)p, y = *(const float4*)(p + 4);
            short8 v;
            v[0]=(short)f2b(x.x); v[1]=(short)f2b(x.y);
            v[2]=(short)f2b(x.z); v[3]=(short)f2b(x.w);
            v[4]=(short)f2b(y.x); v[5]=(short)f2b(y.y);
            v[6]=(short)f2b(y.z); v[7]=(short)f2b(y.w);
            pbv[kk][n2] = v;
        }

    // ALL 4 heads' q -> Aq[head=wn] regions (32KB each); acc dies here.
    // Aq layout per head: [kq=d>>3][row(256)][8].
    #pragma unroll
    for (int mt = 0; mt < 8; ++mt)
        #pragma unroll
        for (int nt = 0; nt < 4; ++nt)
            #pragma unroll
            for (int p = 0; p < 4; ++p) {
                int row = wm*128 + mt*16 + rq*4 + p;
                int d   = nt*16 + lr;
                lds[(size_t)wn*16384 + ((size_t)(d>>3)*256 + row)*8 + (d&7)]
                    = f2b(acc[mt][nt][p]);
            }
    __syncthreads();

    const float ratio = 0.08838834764831845f;
    #pragma unroll
    for (int hs = 0; hs < 4; ++hs) {
        f32x4 a2[8][2];
        const f32x4 z4 = {0.f, 0.f, 0.f, 0.f};
        #pragma unroll
        for (int i = 0; i < 8; ++i) { a2[i][0] = z4; a2[i][1] = z4; }
        #pragma unroll
        for (int kk = 0; kk < 2; ++kk)
            #pragma unroll
            for (int mt = 0; mt < 8; ++mt) {
                short8 av = *(const short8*)(lds + (size_t)hs*16384 +
                    ((size_t)(kk*4 + rq)*256 + wm*128 + mt*16 + lr) * 8);
                #pragma unroll
                for (int n2 = 0; n2 < 2; ++n2)
                    a2[mt][n2] = __builtin_amdgcn_mfma_f32_16x16x32_bf16(
                        av, pbv[kk][n2], a2[mt][n2], 0, 0, 0);
            }
        #pragma unroll
        for (int mt = 0; mt < 8; ++mt)
            #pragma unroll
            for (int n2 = 0; n2 < 2; ++n2)
                #pragma unroll
                for (int p = 0; p < 4; ++p) {
                    size_t rowg = bm + wm*128 + mt*16 + rq*4 + p;
                    int m = wn*32 + n2*16 + lr;
                    float v = fmaxf(a2[mt][n2][p] * ratio, 0.f) + 1e-3f;
                    OUT[(rowg * H_ + (h0 + hs)) * M_ + m] = f2b(v);
                }
    }
}

// ---------------------------------------------------------------------------
// Plain 256^2 GEMM, bf16 out (V projection). grid (4,64), 512 thr.
// ---------------------------------------------------------------------------
__global__ __launch_bounds__(512) void gemm256_bf16(
    const ushort* __restrict__ A, const ushort* __restrict__ BT,
    ushort* __restrict__ C)
{
    __shared__ __align__(16) ushort lds[65536];
    int bx, by; xcd_swz_4x64(bx, by);
    const int bm = by * 256, bn = bx * 256;
    f32x4 acc[8][4];
    zero84(acc);
    gemm256_core(A + (size_t)bm * HID_, BT + (size_t)bn * HID_,
                 HID_, HID_, lds, lds + 32768, acc);
    const int t = threadIdx.x, w = t >> 6, lane = t & 63;
    const int wm = w >> 2, wn = w & 3, lr = lane & 15, rq = lane >> 4;
    #pragma unroll
    for (int mt = 0; mt < 8; ++mt)
        #pragma unroll
        for (int nt = 0; nt < 4; ++nt)
            #pragma unroll
            for (int p = 0; p < 4; ++p) {
                size_t row = bm + wm*128 + mt*16 + rq*4 + p;
                int col = bn + wn*64 + nt*16 + lr;
                C[row * HID_ + col] = f2b(acc[mt][nt][p]);
            }
}

// ---------------------------------------------------------------------------
// Plain 256^2 GEMM, f32 out (output projection). grid (4,64), 512 thr.
// ---------------------------------------------------------------------------
__global__ __launch_bounds__(512) void gemm256_f32(
    const ushort* __restrict__ A, const ushort* __restrict__ BT,
    float* __restrict__ C)
{
    __shared__ __align__(16) ushort lds[65536];
    int bx, by; xcd_swz_4x64(bx, by);
    const int bm = by * 256, bn = bx * 256;
    f32x4 acc[8][4];
    zero84(acc);
    gemm256_core(A + (size_t)bm * HID_, BT + (size_t)bn * HID_,
                 HID_, HID_, lds, lds + 32768, acc);
    const int t = threadIdx.x, w = t >> 6, lane = t & 63;
    const int wm = w >> 2, wn = w & 3, lr = lane & 15, rq = lane >> 4;
    #pragma unroll
    for (int mt = 0; mt < 8; ++mt)
        #pragma unroll
        for (int nt = 0; nt < 4; ++nt)
            #pragma unroll
            for (int p = 0; p < 4; ++p) {
                size_t row = bm + wm*128 + mt*16 + rq*4 + p;
                int col = bn + wn*64 + nt*16 + lr;
                C[row * HID_ + col] = acc[mt][nt][p];
            }
}

// ---------------------------------------------------------------------------
// 128x128-tile MFMA K-loop, 2-phase double-buffered (R4-verified; used by
// numden only, K=128). As/Bs: 8192 ushorts each = 2 x 8KB buffers.
// ---------------------------------------------------------------------------
__device__ __forceinline__ void mfma_gemm_g(
    const ushort* __restrict__ A, const ushort* __restrict__ BT,
    int sA, int sB, int K, ushort* As, ushort* Bs, f32x4 acc[4][4])
{
    const int t = threadIdx.x, w = t >> 6, lane = t & 63;
    const int wm = w >> 1, wn = w & 1, kg = lane >> 4, lr = lane & 15;
    const ushort* a0 = A  + (size_t)lane * sA + w * 8;
    const ushort* a1 = A  + (size_t)(64 + lane) * sA + w * 8;
    const ushort* b0 = BT + (size_t)lane * sB + w * 8;
    const ushort* b1 = BT + (size_t)(64 + lane) * sB + w * 8;
    ushort* lA0 = As + (size_t)(w * 128) * 8;
    ushort* lA1 = As + (size_t)(w * 128 + 64) * 8;
    ushort* lB0 = Bs + (size_t)(w * 128) * 8;
    ushort* lB1 = Bs + (size_t)(w * 128 + 64) * 8;

    gld16(lA0, a0); gld16(lA1, a1); gld16(lB0, b0); gld16(lB1, b1);
    __syncthreads();

    int cur = 0;
    for (int k0 = 0; k0 < K; k0 += 32) {
        const int nxt = cur ^ 1;
        if (k0 + 32 < K) {
            gld16(lA0 + nxt * 4096, a0 + k0 + 32);
            gld16(lA1 + nxt * 4096, a1 + k0 + 32);
            gld16(lB0 + nxt * 4096, b0 + k0 + 32);
            gld16(lB1 + nxt * 4096, b1 + k0 + 32);
        }
        const ushort* Ac = As + cur * 4096;
        const ushort* Bc = Bs + cur * 4096;
        short8 av[4], bv[4];
        #pragma unroll
        for (int i = 0; i < 4; ++i)
            av[i] = *(const short8*)(Ac + ((size_t)kg*128 + wm*64 + i*16 + lr) * 8);
        #pragma unroll
        for (int i = 0; i < 4; ++i)
            bv[i] = *(const short8*)(Bc + ((size_t)kg*128 + wn*64 + i*16 + lr) * 8);
        #pragma unroll
        for (int mt = 0; mt < 4; ++mt)
            #pragma unroll
            for (int nt = 0; nt < 4; ++nt)
                acc[mt][nt] = __builtin_amdgcn_mfma_f32_16x16x32_bf16(
                    av[mt], bv[nt], acc[mt][nt], 0, 0, 0);
        __syncthreads();
        cur = nxt;
    }
}

// ---------------------------------------------------------------------------
// f32 -> bf16 elementwise convert (X inputs)
// ---------------------------------------------------------------------------
__global__ __launch_bounds__(256) void cvt_bf16(
    const float* __restrict__ X, ushort* __restrict__ Y, int n4)
{
    for (int i = blockIdx.x * 256 + threadIdx.x; i < n4; i += gridDim.x * 256) {
        float4 v = ((const float4*)X)[i];
        ushort4 o;
        o.x = f2b(v.x); o.y = f2b(v.y); o.z = f2b(v.z); o.w = f2b(v.w);
        ((ushort4*)Y)[i] = o;
    }
}

// ---------------------------------------------------------------------------
// W[k][n] f32 -> WT[n][k] bf16 (1024x1024), 64x64 tiles
// ---------------------------------------------------------------------------
__global__ __launch_bounds__(256) void wtrans(
    const float* __restrict__ W, ushort* __restrict__ WT)
{
    __shared__ float tile[64][65];
    const int k0 = blockIdx.y * 64, n0 = blockIdx.x * 64;
    const int t = threadIdx.x;
    for (int i = t; i < 1024; i += 256) {
        int r = i >> 4, c4 = i & 15;
        float4 v = *(const float4*)(W + (size_t)(k0 + r) * HID_ + n0 + c4 * 4);
        tile[r][c4*4+0] = v.x; tile[r][c4*4+1] = v.y;
        tile[r][c4*4+2] = v.z; tile[r][c4*4+3] = v.w;
    }
    __syncthreads();
    for (int i = t; i < 1024; i += 256) {
        int n = i >> 4, c4 = i & 15;
        ushort4 o;
        o.x = f2b(tile[c4*4+0][n]); o.y = f2b(tile[c4*4+1][n]);
        o.z = f2b(tile[c4*4+2][n]); o.w = f2b(tile[c4*4+3][n]);
        *(ushort4*)(WT + (size_t)(n0 + n) * HID_ + k0 + c4 * 4) = o;
    }
}

// ---------------------------------------------------------------------------
// KP [l][h][m] -> KPt[bh][m][l] bf16, 128x128 tiles, + per-m column sums
// (ksp[bh][lc][m], f32). XOR block swizzle pb = mq ^ (l>>3).
// grid (bh=64, lc=32).
// ---------------------------------------------------------------------------
__global__ __launch_bounds__(256) void kptrans_kernel(
    const ushort* __restrict__ KP, ushort* __restrict__ KPt,
    float* __restrict__ ksp)
{
    __shared__ __align__(16) ushort tile[128*128];   // 32KB, swizzled blocks
    const int bh = blockIdx.x, lc = blockIdx.y;
    const int b = bh >> 4, h = bh & 15;
    const int t = threadIdx.x;
    const size_t src = ((size_t)(b*L_ + lc*128) * H_ + h) * M_;

    #pragma unroll
    for (int it = 0; it < 8; ++it) {                 // load [l][m] swizzled
        int i = it*256 + t;
        int l = i >> 4, mq = i & 15;
        int pb = mq ^ (l >> 3);
        *(uint4*)&tile[l*128 + pb*8] =
            *(const uint4*)&KP[src + (size_t)l*(H_*M_) + mq*8];
    }
    __syncthreads();

    if (t < 128) {                                   // per-m partial sums
        float s = 0.f;
        for (int l = 0; l < 128; ++l) {
            int pb = (t >> 3) ^ (l >> 3);
            s += b2f(tile[l*128 + pb*8 + (t & 7)]);
        }
        ksp[((size_t)bh*32 + lc)*128 + t] = s;
    }

    #pragma unroll
    for (int it = 0; it < 8; ++it) {                 // transposed write-out
        int i = it*256 + t;
        int m = i >> 4, lq = i & 15;
        short8 v;
        #pragma unroll
        for (int j = 0; j < 8; ++j) {
            int l = lq*8 + j;
            int pb = (m >> 3) ^ lq;                  // l>>3 == lq (j<8)
            v[j] = (short)tile[l*128 + pb*8 + (m & 7)];
        }
        *(short8*)&KPt[((size_t)bh*128 + m)*L_ + lc*128 + lq*8] = v;
    }
}

// ---------------------------------------------------------------------------
// V [l][h][d] -> Vt[bh][d][l] bf16, 128x64 tiles. grid (bh=64, lc=32).
// ---------------------------------------------------------------------------
__global__ __launch_bounds__(256) void vtrans_kernel(
    const ushort* __restrict__ V, ushort* __restrict__ Vt)
{
    __shared__ __align__(16) ushort tile[128*64];    // 16KB, swizzled blocks
    const int bh = blockIdx.x, lc = blockIdx.y;
    const int b = bh >> 4, h = bh & 15;
    const int t = threadIdx.x;
    const size_t src = ((size_t)(b*L_ + lc*128) * H_ + h) * DH_;

    #pragma unroll
    for (int it = 0; it < 4; ++it) {                 // load [l][d] swizzled
        int i = it*256 + t;
        int l = i >> 3, mq = i & 7;
        int pb = mq ^ ((l >> 3) & 7);
        *(uint4*)&tile[l*64 + pb*8] =
            *(const uint4*)&V[src + (size_t)l*(H_*DH_) + mq*8];
    }
    __syncthreads();

    #pragma unroll
    for (int it = 0; it < 4; ++it) {                 // transposed write-out
        int i = it*256 + t;
        int d = i >> 4, lq = i & 15;
        short8 v;
        #pragma unroll
        for (int j = 0; j < 8; ++j) {
            int l = lq*8 + j;
            int pb = (d >> 3) ^ (lq & 7);
            v[j] = (short)tile[l*64 + pb*8 + (d & 7)];
        }
        *(short8*)&Vt[((size_t)bh*64 + d)*L_ + lc*128 + lq*8] = v;
    }
}

// ---------------------------------------------------------------------------
// kvs via MFMA, 2-phase dbuf: per (bh, part), C[d(64)][m(128)] over 512 l.
// A=Vt (64 rows), BT=KPt (128 rows), K=512, k-contig.
// Partials KVSP[part][bh][d][m] f32. grid (bh=64, part=8).
// ---------------------------------------------------------------------------
__global__ __launch_bounds__(256) void kvs_mfma(
    const ushort* __restrict__ Vt, const ushort* __restrict__ KPt,
    float* __restrict__ KVSP)
{
    __shared__ __align__(16) ushort As[4096], Bs[8192];  // 2x4KB, 2x8KB
    const int bh = blockIdx.x, part = blockIdx.y;
    const ushort* A  = Vt  + (size_t)bh * 64  * L_ + part * 512;
    const ushort* BT = KPt + (size_t)bh * 128 * L_ + part * 512;
    const int t = threadIdx.x, w = t >> 6, lane = t & 63;
    const int wm = w >> 1, wn = w & 1, kg = lane >> 4, lr = lane & 15;
    const ushort* a0 = A  + (size_t)lane * L_ + w * 8;
    const ushort* b0 = BT + (size_t)lane * L_ + w * 8;
    const ushort* b1 = BT + (size_t)(64 + lane) * L_ + w * 8;
    ushort* lA0 = As + (size_t)(w * 64) * 8;
    ushort* lB0 = Bs + (size_t)(w * 128) * 8;
    ushort* lB1 = Bs + (size_t)(w * 128 + 64) * 8;

    f32x4 acc[2][4];
    const f32x4 z4 = {0.f, 0.f, 0.f, 0.f};
    #pragma unroll
    for (int mt = 0; mt < 2; ++mt)
        #pragma unroll
        for (int nt = 0; nt < 4; ++nt) acc[mt][nt] = z4;

    gld16(lA0, a0); gld16(lB0, b0); gld16(lB1, b1);
    __syncthreads();

    int cur = 0;
    for (int k0 = 0; k0 < 512; k0 += 32) {
        const int nxt = cur ^ 1;
        if (k0 + 32 < 512) {
            gld16(lA0 + nxt * 2048, a0 + k0 + 32);
            gld16(lB0 + nxt * 4096, b0 + k0 + 32);
            gld16(lB1 + nxt * 4096, b1 + k0 + 32);
        }
        const ushort* Ac = As + cur * 2048;
        const ushort* Bc = Bs + cur * 4096;
        short8 av[2], bv[4];
        #pragma unroll
        for (int i = 0; i < 2; ++i)
            av[i] = *(const short8*)(Ac + ((size_t)kg*64 + wm*32 + i*16 + lr) * 8);
        #pragma unroll
        for (int i = 0; i < 4; ++i)
            bv[i] = *(const short8*)(Bc + ((size_t)kg*128 + wn*64 + i*16 + lr) * 8);
        #pragma unroll
        for (int mt = 0; mt < 2; ++mt)
            #pragma unroll
            for (int nt = 0; nt < 4; ++nt)
                acc[mt][nt] = __builtin_amdgcn_mfma_f32_16x16x32_bf16(
                    av[mt], bv[nt], acc[mt][nt], 0, 0, 0);
        __syncthreads();
        cur = nxt;
    }

    const int rq = lane >> 4;
    #pragma unroll
    for (int mt = 0; mt < 2; ++mt)
        #pragma unroll
        for (int nt = 0; nt < 4; ++nt)
            #pragma unroll
            for (int p = 0; p < 4; ++p) {
                int row = wm*32 + mt*16 + rq*4 + p;        // d
                int col = wn*64 + nt*16 + lr;              // m
                KVSP[(((size_t)part*64 + bh)*64 + row)*128 + col]
                    = acc[mt][nt][p];
            }
}

// ---------------------------------------------------------------------------
// kvs_reduce: sum 8 KVS partials + 32 ksp partials -> bf16
// KVSt[bh][d][m] (d<64) = kvs; [64][m] = ks_sum; [65..127][m] = 0
// ---------------------------------------------------------------------------
__global__ __launch_bounds__(256) void kvs_reduce_kernel(
    const float* __restrict__ KVSP, const float* __restrict__ ksp,
    ushort* __restrict__ KVSt)
{
    const int bh = blockIdx.x;
    for (int i = threadIdx.x; i < 128*128; i += 256) {
        int d = i >> 7, m = i & 127;
        ushort v = 0;
        if (d < 64) {
            float s = 0.f;
            #pragma unroll
            for (int p = 0; p < 8; ++p)
                s += KVSP[(((size_t)p*64 + bh)*64 + d)*128 + m];
            v = f2b(s);
        } else if (d == 64) {
            float s = 0.f;
            #pragma unroll
            for (int c = 0; c < 32; ++c)
                s += ksp[((size_t)bh*32 + c)*128 + m];
            v = f2b(s);
        }
        KVSt[(size_t)bh * 16384 + i] = v;
    }
}

// ---------------------------------------------------------------------------
// numden: per (b,h), 128-row tile: [QP rows, K=128 m] x KVSt[128][128].
// Output cols 0..63 = num, col 64 = den -> ATT = num/den (bf16) directly.
// grid (bh=64, L/128=32).
// ---------------------------------------------------------------------------
__global__ __launch_bounds__(256) void numden_mfma(
    const ushort* __restrict__ QP, const ushort* __restrict__ KVSt,
    ushort* __restrict__ ATT)
{
    __shared__ __align__(16) ushort As[8192], Bs[8192];
    __shared__ float sden[128];
    const int bh = blockIdx.x, b = bh >> 4, h = bh & 15;
    const int l0 = blockIdx.y * 128;
    const ushort* Abase = QP + ((size_t)(b * L_ + l0) * H_ + h) * M_;
    const ushort* Bbase = KVSt + (size_t)bh * 16384;

    f32x4 acc[4][4];
    const f32x4 z4 = {0.f, 0.f, 0.f, 0.f};
    #pragma unroll
    for (int mt = 0; mt < 4; ++mt)
        #pragma unroll
        for (int nt = 0; nt < 4; ++nt) acc[mt][nt] = z4;

    mfma_gemm_g(Abase, Bbase, H_*M_, 128, 128, As, Bs, acc);

    const int t = threadIdx.x, w = t >> 6, lane = t & 63;
    const int wm = w >> 1, wn = w & 1, lr = lane & 15, rq = lane >> 4;

    if (wn == 1 && lr == 0) {       // col 64 = den
        #pragma unroll
        for (int mt = 0; mt < 4; ++mt)
            #pragma unroll
            for (int p = 0; p < 4; ++p)
                sden[wm*64 + mt*16 + rq*4 + p] = acc[mt][0][p];
    }
    __syncthreads();

    if (wn == 0) {
        #pragma unroll
        for (int mt = 0; mt < 4; ++mt) {
            #pragma unroll
            for (int p = 0; p < 4; ++p) {
                int row = wm*64 + mt*16 + rq*4 + p;
                float den = fmaxf(sden[row], 1e-10f);
                float rden = 1.0f / den;
                size_t gbase = (size_t)(b * L_ + l0 + row) * HID_ + h * DH_;
                #pragma unroll
                for (int nt = 0; nt < 4; ++nt)
                    ATT[gbase + nt*16 + lr] = f2b(acc[mt][nt][p] * rden);
            }
        }
    }
}

// ---------------------------------------------------------------------------
extern "C" void kernel_launch(void* const* d_in, const int* in_sizes, int n_in,
                              void* d_out, int out_size, void* d_ws, size_t ws_size,
                              hipStream_t stream)
{
    const float* Xq = (const float*)d_in[0];
    const float* Xs = (const float*)d_in[1];
    const float* Wq = (const float*)d_in[2];
    const float* Wk = (const float*)d_in[3];
    const float* Wv = (const float*)d_in[4];
    const float* Wo = (const float*)d_in[5];
    const float* Pj = (const float*)d_in[6];
    float* out = (float*)d_out;

    // Workspace layout (MB-aligned, audited disjoint per stage / safe alias):
    //   WqT..WoT [0,8)  Xqb [8,40)  Xsb [40,72)  QPb [72,136)
    //   KPb [136,200)   Vb [200,232)
    //   KPt  [8,72)    alias Xqb+Xsb  (dead after gemms)
    //   Vt   [136,168) alias KPb-lo   (KPb dead after kptrans)
    //   KVSP [168,184) alias KPb-mid
    //   KVSt [184,186) alias KPb-hi
    //   ksp  [0,1)     alias WqT      (dead after Q-gemm)
    //   ATT  [200,232) alias Vb       (dead after vtrans)
    char* ws = (char*)d_ws;
    ushort* WqT = (ushort*)(ws + 0);
    ushort* WkT = (ushort*)(ws + 2097152);
    ushort* WvT = (ushort*)(ws + 4194304);
    ushort* WoT = (ushort*)(ws + 6291456);
    ushort* Xqb = (ushort*)(ws + 8388608);
    ushort* Xsb = (ushort*)(ws + 41943040);
    ushort* QPb = (ushort*)(ws + 75497472);
    ushort* KPb = (ushort*)(ws + 142606336);
    ushort* Vb  = (ushort*)(ws + 209715200);
    ushort* KPt = (ushort*)(ws + 8388608);        // 64MB
    ushort* Vt  = (ushort*)(ws + 142606336);      // 32MB
    float*  KVSP = (float*)(ws + 176160768);      // 16MB
    ushort* KVSt = (ushort*)(ws + 192937984);     // 2MB
    float*  ksp  = (float*)(ws + 0);              // 1MB
    ushort* ATT  = Vb;

    dim3 tb(256);
    dim3 tb512(512);

    cvt_bf16<<<4096, tb, 0, stream>>>(Xq, Xqb, BL_*HID_/4);
    cvt_bf16<<<4096, tb, 0, stream>>>(Xs, Xsb, BL_*HID_/4);
    wtrans<<<dim3(16,16), tb, 0, stream>>>(Wq, WqT);
    wtrans<<<dim3(16,16), tb, 0, stream>>>(Wk, WkT);
    wtrans<<<dim3(16,16), tb, 0, stream>>>(Wv, WvT);
    wtrans<<<dim3(16,16), tb, 0, stream>>>(Wo, WoT);

    gemm_phi_mfma256<<<dim3(4, 64), tb512, 0, stream>>>(Xqb, WqT, Pj, QPb);
    gemm_phi_mfma256<<<dim3(4, 64), tb512, 0, stream>>>(Xsb, WkT, Pj, KPb);
    gemm256_bf16<<<dim3(4, 64), tb512, 0, stream>>>(Xsb, WvT, Vb);

    kptrans_kernel<<<dim3(64, 32), tb, 0, stream>>>(KPb, KPt, ksp);
    vtrans_kernel<<<dim3(64, 32), tb, 0, stream>>>(Vb, Vt);

    kvs_mfma<<<dim3(64, 8), tb, 0, stream>>>(Vt, KPt, KVSP);
    kvs_reduce_kernel<<<64, tb, 0, stream>>>(KVSP, ksp, KVSt);

    numden_mfma<<<dim3(B_*H_, L_/128), tb, 0, stream>>>(QPb, KVSt, ATT);

    gemm256_f32<<<dim3(4, 64), tb512, 0, stream>>>(ATT, WoT, out);
    (void)in_sizes; (void)n_in; (void)out_size; (void)ws_size;
}

// Round 7
// 483.402 us; speedup vs baseline: 1.2927x; 1.0586x over previous
//
#include <hip/hip_runtime.h>
#include <hip/hip_bf16.h>

// Performer / FAVOR+ noncausal attention. ALL inputs + output FLOAT32.
// Intermediates bf16/f32. MFMA (16x16x32 bf16) for GEMMs + fused num/den.
// This revision (vs R6): 256^2 core converted from per-tile vmcnt(0)-drain
// (__syncthreads) to HALF-TILE counted-vmcnt pipeline (m201/m218 lever):
// phases = C-quadrants (128x128, all 8 waves cooperate, 64x32/wave), so
// phase (r,c) needs only A-half r + B-half c. Tile = 4 stage units
// (A0,B0,B1,A1; 2 gld16/thread each). One unit of tile t+1 staged per
// phase; vmcnt(4) before phases 0,1,2 (needed unit = oldest outstanding),
// no wait at phase 3. 3 barriers/tile, loads never drained to 0 in-loop.
// Tail tile peeled with vmcnt(4)/(2)/(0).
#define B_   4
#define L_   4096
#define HID_ 1024
#define H_   16
#define DH_  64
#define M_   128
#define BL_  (B_*L_)        // 16384
#define NROW (BL_*H_)       // 262144

using short8 = __attribute__((ext_vector_type(8))) short;
using f32x4  = __attribute__((ext_vector_type(4))) float;

__device__ __forceinline__ float b2f(ushort s) {
    return __builtin_bit_cast(float, (unsigned int)s << 16);
}
__device__ __forceinline__ ushort f2b(float f) {  // RNE
    unsigned int u = __builtin_bit_cast(unsigned int, f);
    u += 0x7fffu + ((u >> 16) & 1u);
    return (ushort)(u >> 16);
}

// async global->LDS, 16B per lane; LDS dest = wave-uniform base + lane*16
__device__ __forceinline__ void gld16(void* lds, const void* g) {
    __builtin_amdgcn_global_load_lds(
        (const __attribute__((address_space(1))) unsigned int*)g,
        (__attribute__((address_space(3))) unsigned int*)lds, 16, 0, 0);
}

#define VMCNT4 asm volatile("s_waitcnt vmcnt(4)" ::: "memory")
#define VMCNT2 asm volatile("s_waitcnt vmcnt(2)" ::: "memory")
#define VMCNT0 asm volatile("s_waitcnt vmcnt(0)" ::: "memory")
#define SBAR do { __builtin_amdgcn_sched_barrier(0); \
                  __builtin_amdgcn_s_barrier(); \
                  __builtin_amdgcn_sched_barrier(0); } while (0)

// XCD-chunked bijective remap, grid (4,64) = 256 blocks (256%8==0).
__device__ __forceinline__ void xcd_swz_4x64(int& bx, int& by) {
    int orig = (int)blockIdx.x + ((int)blockIdx.y << 2);
    int nu = ((orig & 7) << 5) + (orig >> 3);
    bx = nu & 3; by = nu >> 2;
}

// ---------------------------------------------------------------------------
// 256x256-tile 8-wave MFMA core, K=1024 (16 K-tiles of BK=64), counted-vmcnt
// half-tile pipeline. LDS (128KB, caller provides 65536 ushorts):
//   A: [buf(2)][half(2)][kq(8)][row128][8] at lds[0..32768)
//   B: [buf(2)][half(2)][kq(8)][col128][8] at lds[32768..65536)
// Wave w stages kq=w. Phases = C-quadrants (r,c); wave sub-tile 64x32 at
// rows r*128+wr*64, cols c*128+wc*32 (wr=w>>2, wc=w&3). acc[r][c][4][2].
// ---------------------------------------------------------------------------
__device__ __forceinline__ void gemm256_core(
    const ushort* __restrict__ A, const ushort* __restrict__ BT,
    int sA, int sB, ushort* lds, f32x4 acc[2][2][4][2])
{
    const int t = threadIdx.x, w = t >> 6, lane = t & 63;
    const int wr = (w >> 2) & 1, wc = w & 3, kg = lane >> 4, lr = lane & 15;
    ushort* LA = lds;
    ushort* LB = lds + 32768;

    auto stageA = [&](int b, int hf, int kt) {
        ushort* l = LA + ((size_t)((b*2 + hf)*8 + w)) * 1024;
        const ushort* g = A + (size_t)(hf*128 + lane) * sA + kt*64 + w*8;
        gld16(l,       g);
        gld16(l + 512, g + (size_t)64 * sA);
    };
    auto stageB = [&](int b, int hf, int kt) {
        ushort* l = LB + ((size_t)((b*2 + hf)*8 + w)) * 1024;
        const ushort* g = BT + (size_t)(hf*128 + lane) * sB + kt*64 + w*8;
        gld16(l,       g);
        gld16(l + 512, g + (size_t)64 * sB);
    };

    short8 av[2][4], bv[2][2];
    auto loadA = [&](int b, int r) {
        #pragma unroll
        for (int kk = 0; kk < 2; ++kk)
            #pragma unroll
            for (int i = 0; i < 4; ++i)
                av[kk][i] = *(const short8*)(LA
                    + ((size_t)((b*2 + r)*8 + kk*4 + kg)) * 1024
                    + (size_t)(wr*64 + i*16 + lr) * 8);
    };
    auto loadB = [&](int b, int c) {
        #pragma unroll
        for (int kk = 0; kk < 2; ++kk)
            #pragma unroll
            for (int j = 0; j < 2; ++j)
                bv[kk][j] = *(const short8*)(LB
                    + ((size_t)((b*2 + c)*8 + kk*4 + kg)) * 1024
                    + (size_t)(wc*32 + j*16 + lr) * 8);
    };
    auto mfma16 = [&](int r, int c) {
        __builtin_amdgcn_s_setprio(1);
        #pragma unroll
        for (int kk = 0; kk < 2; ++kk)
            #pragma unroll
            for (int i = 0; i < 4; ++i)
                #pragma unroll
                for (int j = 0; j < 2; ++j)
                    acc[r][c][i][j] = __builtin_amdgcn_mfma_f32_16x16x32_bf16(
                        av[kk][i], bv[kk][j], acc[r][c][i][j], 0, 0, 0);
        __builtin_amdgcn_s_setprio(0);
    };

    // prologue: tile 0's 4 units, in consumption order
    stageA(0, 0, 0); stageB(0, 0, 0); stageB(0, 1, 0); stageA(0, 1, 0);

    for (int kt = 0; kt < 15; ++kt) {
        const int b = kt & 1, nb = b ^ 1;
        VMCNT4; SBAR;                       // A0,B0 of tile kt landed (all waves)
        loadA(b, 0); loadB(b, 0);
        stageA(nb, 0, kt + 1);
        mfma16(0, 0);
        VMCNT4; SBAR;                       // B1 landed
        loadB(b, 1);
        stageB(nb, 0, kt + 1);
        mfma16(0, 1);
        VMCNT4; SBAR;                       // A1 landed
        loadA(b, 1);
        stageB(nb, 1, kt + 1);
        mfma16(1, 1);
        loadB(b, 0);                        // B0 still valid, no wait needed
        stageA(nb, 1, kt + 1);
        mfma16(1, 0);
    }
    {   // tail tile 15 (buffer 1), no staging; drain progressively
        VMCNT4; SBAR;
        loadA(1, 0); loadB(1, 0); mfma16(0, 0);
        VMCNT2; SBAR;
        loadB(1, 1); mfma16(0, 1);
        VMCNT0; SBAR;
        loadA(1, 1); mfma16(1, 1);
        loadB(1, 0); mfma16(1, 0);
    }
    __syncthreads();                        // LDS safe for caller reuse
}

__device__ __forceinline__ void zero224(f32x4 acc[2][2][4][2]) {
    const f32x4 z4 = {0.f, 0.f, 0.f, 0.f};
    #pragma unroll
    for (int r = 0; r < 2; ++r)
        #pragma unroll
        for (int c = 0; c < 2; ++c)
            #pragma unroll
            for (int i = 0; i < 4; ++i)
                #pragma unroll
                for (int j = 0; j < 2; ++j) acc[r][c][i][j] = z4;
}

// ---------------------------------------------------------------------------
// Fused QK projection + phi, 256^2 core. grid (HID/256=4, BL/256=64), 512thr.
// Block covers heads h0=4*bx..+3. After the main GEMM all 4 heads' q go to
// the dead 128KB LDS in A-operand layout [head][kq][row256][8], then
// per-head phi [256x64] x projT -> [256x128]. proj frags in registers.
// ---------------------------------------------------------------------------
__global__ __launch_bounds__(512) void gemm_phi_mfma256(
    const ushort* __restrict__ A, const ushort* __restrict__ BT,
    const float* __restrict__ proj, ushort* __restrict__ OUT)
{
    __shared__ __align__(16) ushort lds[65536];  // 128KB
    int bx, by; xcd_swz_4x64(bx, by);
    const int bm = by * 256, bn = bx * 256, h0 = bx * 4;

    f32x4 acc[2][2][4][2];
    zero224(acc);
    gemm256_core(A + (size_t)bm * HID_, BT + (size_t)bn * HID_,
                 HID_, HID_, lds, acc);

    const int t = threadIdx.x, w = t >> 6, lane = t & 63;
    const int wr = (w >> 2) & 1, wc = w & 3, lr = lane & 15, rq = lane >> 4;

    // proj fragments (head-independent): m = wc*32 + j2*16 + lr
    short8 pbv[2][2];
    #pragma unroll
    for (int kk = 0; kk < 2; ++kk)
        #pragma unroll
        for (int n2 = 0; n2 < 2; ++n2) {
            const float* p = proj + (size_t)(wc*32 + n2*16 + lr) * DH_
                                  + (kk*4 + rq) * 8;
            float4 x = *(const float4*)p, y = *(const float4*)(p + 4);
            short8 v;
            v[0]=(short)f2b(x.x); v[1]=(short)f2b(x.y);
            v[2]=(short)f2b(x.z); v[3]=(short)f2b(x.w);
            v[4]=(short)f2b(y.x); v[5]=(short)f2b(y.y);
            v[6]=(short)f2b(y.z); v[7]=(short)f2b(y.w);
            pbv[kk][n2] = v;
        }

    // ALL 4 heads' q -> Aq[head][kq=d>>3][row256][8]; acc dies here.
    // col = c*128 + wc*32 + j*16 + lr -> head = c*2+(wc>>1), d = (wc&1)*32+j*16+lr
    #pragma unroll
    for (int r = 0; r < 2; ++r)
        #pragma unroll
        for (int c = 0; c < 2; ++c)
            #pragma unroll
            for (int i = 0; i < 4; ++i)
                #pragma unroll
                for (int j = 0; j < 2; ++j)
                    #pragma unroll
                    for (int p = 0; p < 4; ++p) {
                        int row = r*128 + wr*64 + i*16 + rq*4 + p;
                        int hs  = c*2 + (wc >> 1);
                        int d   = (wc & 1)*32 + j*16 + lr;
                        lds[(size_t)hs*16384 + ((size_t)(d>>3)*256 + row)*8 + (d&7)]
                            = f2b(acc[r][c][i][j][p]);
                    }
    __syncthreads();

    const float ratio = 0.08838834764831845f;
    const int wm = w >> 2;   // 0..1 row-half for phi stage
    #pragma unroll
    for (int hs = 0; hs < 4; ++hs) {
        f32x4 a2[8][2];
        const f32x4 z4 = {0.f, 0.f, 0.f, 0.f};
        #pragma unroll
        for (int i = 0; i < 8; ++i) { a2[i][0] = z4; a2[i][1] = z4; }
        #pragma unroll
        for (int kk = 0; kk < 2; ++kk)
            #pragma unroll
            for (int mt = 0; mt < 8; ++mt) {
                short8 av = *(const short8*)(lds + (size_t)hs*16384 +
                    ((size_t)(kk*4 + rq)*256 + wm*128 + mt*16 + lr) * 8);
                #pragma unroll
                for (int n2 = 0; n2 < 2; ++n2)
                    a2[mt][n2] = __builtin_amdgcn_mfma_f32_16x16x32_bf16(
                        av, pbv[kk][n2], a2[mt][n2], 0, 0, 0);
            }
        #pragma unroll
        for (int mt = 0; mt < 8; ++mt)
            #pragma unroll
            for (int n2 = 0; n2 < 2; ++n2)
                #pragma unroll
                for (int p = 0; p < 4; ++p) {
                    size_t rowg = bm + wm*128 + mt*16 + rq*4 + p;
                    int m = wc*32 + n2*16 + lr;
                    float v = fmaxf(a2[mt][n2][p] * ratio, 0.f) + 1e-3f;
                    OUT[(rowg * H_ + (h0 + hs)) * M_ + m] = f2b(v);
                }
    }
}

// ---------------------------------------------------------------------------
// Plain 256^2 GEMM, bf16 out (V projection). grid (4,64), 512 thr.
// ---------------------------------------------------------------------------
__global__ __launch_bounds__(512) void gemm256_bf16(
    const ushort* __restrict__ A, const ushort* __restrict__ BT,
    ushort* __restrict__ C)
{
    __shared__ __align__(16) ushort lds[65536];
    int bx, by; xcd_swz_4x64(bx, by);
    const int bm = by * 256, bn = bx * 256;
    f32x4 acc[2][2][4][2];
    zero224(acc);
    gemm256_core(A + (size_t)bm * HID_, BT + (size_t)bn * HID_,
                 HID_, HID_, lds, acc);
    const int t = threadIdx.x, w = t >> 6, lane = t & 63;
    const int wr = (w >> 2) & 1, wc = w & 3, lr = lane & 15, rq = lane >> 4;
    #pragma unroll
    for (int r = 0; r < 2; ++r)
        #pragma unroll
        for (int c = 0; c < 2; ++c)
            #pragma unroll
            for (int i = 0; i < 4; ++i)
                #pragma unroll
                for (int j = 0; j < 2; ++j)
                    #pragma unroll
                    for (int p = 0; p < 4; ++p) {
                        size_t row = bm + r*128 + wr*64 + i*16 + rq*4 + p;
                        int col = bn + c*128 + wc*32 + j*16 + lr;
                        C[row * HID_ + col] = f2b(acc[r][c][i][j][p]);
                    }
}

// ---------------------------------------------------------------------------
// Plain 256^2 GEMM, f32 out (output projection). grid (4,64), 512 thr.
// ---------------------------------------------------------------------------
__global__ __launch_bounds__(512) void gemm256_f32(
    const ushort* __restrict__ A, const ushort* __restrict__ BT,
    float* __restrict__ C)
{
    __shared__ __align__(16) ushort lds[65536];
    int bx, by; xcd_swz_4x64(bx, by);
    const int bm = by * 256, bn = bx * 256;
    f32x4 acc[2][2][4][2];
    zero224(acc);
    gemm256_core(A + (size_t)bm * HID_, BT + (size_t)bn * HID_,
                 HID_, HID_, lds, acc);
    const int t = threadIdx.x, w = t >> 6, lane = t & 63;
    const int wr = (w >> 2) & 1, wc = w & 3, lr = lane & 15, rq = lane >> 4;
    #pragma unroll
    for (int r = 0; r < 2; ++r)
        #pragma unroll
        for (int c = 0; c < 2; ++c)
            #pragma unroll
            for (int i = 0; i < 4; ++i)
                #pragma unroll
                for (int j = 0; j < 2; ++j)
                    #pragma unroll
                    for (int p = 0; p < 4; ++p) {
                        size_t row = bm + r*128 + wr*64 + i*16 + rq*4 + p;
                        int col = bn + c*128 + wc*32 + j*16 + lr;
                        C[row * HID_ + col] = acc[r][c][i][j][p];
                    }
}

// ---------------------------------------------------------------------------
// 128x128-tile MFMA K-loop, 2-phase double-buffered (R4-verified; numden).
// ---------------------------------------------------------------------------
__device__ __forceinline__ void mfma_gemm_g(
    const ushort* __restrict__ A, const ushort* __restrict__ BT,
    int sA, int sB, int K, ushort* As, ushort* Bs, f32x4 acc[4][4])
{
    const int t = threadIdx.x, w = t >> 6, lane = t & 63;
    const int wm = w >> 1, wn = w & 1, kg = lane >> 4, lr = lane & 15;
    const ushort* a0 = A  + (size_t)lane * sA + w * 8;
    const ushort* a1 = A  + (size_t)(64 + lane) * sA + w * 8;
    const ushort* b0 = BT + (size_t)lane * sB + w * 8;
    const ushort* b1 = BT + (size_t)(64 + lane) * sB + w * 8;
    ushort* lA0 = As + (size_t)(w * 128) * 8;
    ushort* lA1 = As + (size_t)(w * 128 + 64) * 8;
    ushort* lB0 = Bs + (size_t)(w * 128) * 8;
    ushort* lB1 = Bs + (size_t)(w * 128 + 64) * 8;

    gld16(lA0, a0); gld16(lA1, a1); gld16(lB0, b0); gld16(lB1, b1);
    __syncthreads();

    int cur = 0;
    for (int k0 = 0; k0 < K; k0 += 32) {
        const int nxt = cur ^ 1;
        if (k0 + 32 < K) {
            gld16(lA0 + nxt * 4096, a0 + k0 + 32);
            gld16(lA1 + nxt * 4096, a1 + k0 + 32);
            gld16(lB0 + nxt * 4096, b0 + k0 + 32);
            gld16(lB1 + nxt * 4096, b1 + k0 + 32);
        }
        const ushort* Ac = As + cur * 4096;
        const ushort* Bc = Bs + cur * 4096;
        short8 av[4], bv[4];
        #pragma unroll
        for (int i = 0; i < 4; ++i)
            av[i] = *(const short8*)(Ac + ((size_t)kg*128 + wm*64 + i*16 + lr) * 8);
        #pragma unroll
        for (int i = 0; i < 4; ++i)
            bv[i] = *(const short8*)(Bc + ((size_t)kg*128 + wn*64 + i*16 + lr) * 8);
        #pragma unroll
        for (int mt = 0; mt < 4; ++mt)
            #pragma unroll
            for (int nt = 0; nt < 4; ++nt)
                acc[mt][nt] = __builtin_amdgcn_mfma_f32_16x16x32_bf16(
                    av[mt], bv[nt], acc[mt][nt], 0, 0, 0);
        __syncthreads();
        cur = nxt;
    }
}

// ---------------------------------------------------------------------------
// f32 -> bf16 elementwise convert (X inputs)
// ---------------------------------------------------------------------------
__global__ __launch_bounds__(256) void cvt_bf16(
    const float* __restrict__ X, ushort* __restrict__ Y, int n4)
{
    for (int i = blockIdx.x * 256 + threadIdx.x; i < n4; i += gridDim.x * 256) {
        float4 v = ((const float4*)X)[i];
        ushort4 o;
        o.x = f2b(v.x); o.y = f2b(v.y); o.z = f2b(v.z); o.w = f2b(v.w);
        ((ushort4*)Y)[i] = o;
    }
}

// ---------------------------------------------------------------------------
// W[k][n] f32 -> WT[n][k] bf16 (1024x1024), 64x64 tiles
// ---------------------------------------------------------------------------
__global__ __launch_bounds__(256) void wtrans(
    const float* __restrict__ W, ushort* __restrict__ WT)
{
    __shared__ float tile[64][65];
    const int k0 = blockIdx.y * 64, n0 = blockIdx.x * 64;
    const int t = threadIdx.x;
    for (int i = t; i < 1024; i += 256) {
        int r = i >> 4, c4 = i & 15;
        float4 v = *(const float4*)(W + (size_t)(k0 + r) * HID_ + n0 + c4 * 4);
        tile[r][c4*4+0] = v.x; tile[r][c4*4+1] = v.y;
        tile[r][c4*4+2] = v.z; tile[r][c4*4+3] = v.w;
    }
    __syncthreads();
    for (int i = t; i < 1024; i += 256) {
        int n = i >> 4, c4 = i & 15;
        ushort4 o;
        o.x = f2b(tile[c4*4+0][n]); o.y = f2b(tile[c4*4+1][n]);
        o.z = f2b(tile[c4*4+2][n]); o.w = f2b(tile[c4*4+3][n]);
        *(ushort4*)(WT + (size_t)(n0 + n) * HID_ + k0 + c4 * 4) = o;
    }
}

// ---------------------------------------------------------------------------
// KP [l][h][m] -> KPt[bh][m][l] bf16, 128x128 tiles, + per-m column sums
// (ksp[bh][lc][m], f32). XOR block swizzle pb = mq ^ (l>>3).
// grid (bh=64, lc=32).
// ---------------------------------------------------------------------------
__global__ __launch_bounds__(256) void kptrans_kernel(
    const ushort* __restrict__ KP, ushort* __restrict__ KPt,
    float* __restrict__ ksp)
{
    __shared__ __align__(16) ushort tile[128*128];   // 32KB, swizzled blocks
    const int bh = blockIdx.x, lc = blockIdx.y;
    const int b = bh >> 4, h = bh & 15;
    const int t = threadIdx.x;
    const size_t src = ((size_t)(b*L_ + lc*128) * H_ + h) * M_;

    #pragma unroll
    for (int it = 0; it < 8; ++it) {                 // load [l][m] swizzled
        int i = it*256 + t;
        int l = i >> 4, mq = i & 15;
        int pb = mq ^ (l >> 3);
        *(uint4*)&tile[l*128 + pb*8] =
            *(const uint4*)&KP[src + (size_t)l*(H_*M_) + mq*8];
    }
    __syncthreads();

    if (t < 128) {                                   // per-m partial sums
        float s = 0.f;
        for (int l = 0; l < 128; ++l) {
            int pb = (t >> 3) ^ (l >> 3);
            s += b2f(tile[l*128 + pb*8 + (t & 7)]);
        }
        ksp[((size_t)bh*32 + lc)*128 + t] = s;
    }

    #pragma unroll
    for (int it = 0; it < 8; ++it) {                 // transposed write-out
        int i = it*256 + t;
        int m = i >> 4, lq = i & 15;
        short8 v;
        #pragma unroll
        for (int j = 0; j < 8; ++j) {
            int l = lq*8 + j;
            int pb = (m >> 3) ^ lq;                  // l>>3 == lq (j<8)
            v[j] = (short)tile[l*128 + pb*8 + (m & 7)];
        }
        *(short8*)&KPt[((size_t)bh*128 + m)*L_ + lc*128 + lq*8] = v;
    }
}

// ---------------------------------------------------------------------------
// V [l][h][d] -> Vt[bh][d][l] bf16, 128x64 tiles. grid (bh=64, lc=32).
// ---------------------------------------------------------------------------
__global__ __launch_bounds__(256) void vtrans_kernel(
    const ushort* __restrict__ V, ushort* __restrict__ Vt)
{
    __shared__ __align__(16) ushort tile[128*64];    // 16KB, swizzled blocks
    const int bh = blockIdx.x, lc = blockIdx.y;
    const int b = bh >> 4, h = bh & 15;
    const int t = threadIdx.x;
    const size_t src = ((size_t)(b*L_ + lc*128) * H_ + h) * DH_;

    #pragma unroll
    for (int it = 0; it < 4; ++it) {                 // load [l][d] swizzled
        int i = it*256 + t;
        int l = i >> 3, mq = i & 7;
        int pb = mq ^ ((l >> 3) & 7);
        *(uint4*)&tile[l*64 + pb*8] =
            *(const uint4*)&V[src + (size_t)l*(H_*DH_) + mq*8];
    }
    __syncthreads();

    #pragma unroll
    for (int it = 0; it < 4; ++it) {                 // transposed write-out
        int i = it*256 + t;
        int d = i >> 4, lq = i & 15;
        short8 v;
        #pragma unroll
        for (int j = 0; j < 8; ++j) {
            int l = lq*8 + j;
            int pb = (d >> 3) ^ (lq & 7);
            v[j] = (short)tile[l*64 + pb*8 + (d & 7)];
        }
        *(short8*)&Vt[((size_t)bh*64 + d)*L_ + lc*128 + lq*8] = v;
    }
}

// ---------------------------------------------------------------------------
// kvs via MFMA, 2-phase dbuf: per (bh, part), C[d(64)][m(128)] over 512 l.
// A=Vt (64 rows), BT=KPt (128 rows), K=512, k-contig.
// Partials KVSP[part][bh][d][m] f32. grid (bh=64, part=8).
// ---------------------------------------------------------------------------
__global__ __launch_bounds__(256) void kvs_mfma(
    const ushort* __restrict__ Vt, const ushort* __restrict__ KPt,
    float* __restrict__ KVSP)
{
    __shared__ __align__(16) ushort As[4096], Bs[8192];  // 2x4KB, 2x8KB
    const int bh = blockIdx.x, part = blockIdx.y;
    const ushort* A  = Vt  + (size_t)bh * 64  * L_ + part * 512;
    const ushort* BT = KPt + (size_t)bh * 128 * L_ + part * 512;
    const int t = threadIdx.x, w = t >> 6, lane = t & 63;
    const int wm = w >> 1, wn = w & 1, kg = lane >> 4, lr = lane & 15;
    const ushort* a0 = A  + (size_t)lane * L_ + w * 8;
    const ushort* b0 = BT + (size_t)lane * L_ + w * 8;
    const ushort* b1 = BT + (size_t)(64 + lane) * L_ + w * 8;
    ushort* lA0 = As + (size_t)(w * 64) * 8;
    ushort* lB0 = Bs + (size_t)(w * 128) * 8;
    ushort* lB1 = Bs + (size_t)(w * 128 + 64) * 8;

    f32x4 acc[2][4];
    const f32x4 z4 = {0.f, 0.f, 0.f, 0.f};
    #pragma unroll
    for (int mt = 0; mt < 2; ++mt)
        #pragma unroll
        for (int nt = 0; nt < 4; ++nt) acc[mt][nt] = z4;

    gld16(lA0, a0); gld16(lB0, b0); gld16(lB1, b1);
    __syncthreads();

    int cur = 0;
    for (int k0 = 0; k0 < 512; k0 += 32) {
        const int nxt = cur ^ 1;
        if (k0 + 32 < 512) {
            gld16(lA0 + nxt * 2048, a0 + k0 + 32);
            gld16(lB0 + nxt * 4096, b0 + k0 + 32);
            gld16(lB1 + nxt * 4096, b1 + k0 + 32);
        }
        const ushort* Ac = As + cur * 2048;
        const ushort* Bc = Bs + cur * 4096;
        short8 av[2], bv[4];
        #pragma unroll
        for (int i = 0; i < 2; ++i)
            av[i] = *(const short8*)(Ac + ((size_t)kg*64 + wm*32 + i*16 + lr) * 8);
        #pragma unroll
        for (int i = 0; i < 4; ++i)
            bv[i] = *(const short8*)(Bc + ((size_t)kg*128 + wn*64 + i*16 + lr) * 8);
        #pragma unroll
        for (int mt = 0; mt < 2; ++mt)
            #pragma unroll
            for (int nt = 0; nt < 4; ++nt)
                acc[mt][nt] = __builtin_amdgcn_mfma_f32_16x16x32_bf16(
                    av[mt], bv[nt], acc[mt][nt], 0, 0, 0);
        __syncthreads();
        cur = nxt;
    }

    const int rq = lane >> 4;
    #pragma unroll
    for (int mt = 0; mt < 2; ++mt)
        #pragma unroll
        for (int nt = 0; nt < 4; ++nt)
            #pragma unroll
            for (int p = 0; p < 4; ++p) {
                int row = wm*32 + mt*16 + rq*4 + p;        // d
                int col = wn*64 + nt*16 + lr;              // m
                KVSP[(((size_t)part*64 + bh)*64 + row)*128 + col]
                    = acc[mt][nt][p];
            }
}

// ---------------------------------------------------------------------------
// kvs_reduce: sum 8 KVS partials + 32 ksp partials -> bf16
// KVSt[bh][d][m] (d<64) = kvs; [64][m] = ks_sum; [65..127][m] = 0
// ---------------------------------------------------------------------------
__global__ __launch_bounds__(256) void kvs_reduce_kernel(
    const float* __restrict__ KVSP, const float* __restrict__ ksp,
    ushort* __restrict__ KVSt)
{
    const int bh = blockIdx.x;
    for (int i = threadIdx.x; i < 128*128; i += 256) {
        int d = i >> 7, m = i & 127;
        ushort v = 0;
        if (d < 64) {
            float s = 0.f;
            #pragma unroll
            for (int p = 0; p < 8; ++p)
                s += KVSP[(((size_t)p*64 + bh)*64 + d)*128 + m];
            v = f2b(s);
        } else if (d == 64) {
            float s = 0.f;
            #pragma unroll
            for (int c = 0; c < 32; ++c)
                s += ksp[((size_t)bh*32 + c)*128 + m];
            v = f2b(s);
        }
        KVSt[(size_t)bh * 16384 + i] = v;
    }
}

// ---------------------------------------------------------------------------
// numden: per (b,h), 128-row tile: [QP rows, K=128 m] x KVSt[128][128].
// Output cols 0..63 = num, col 64 = den -> ATT = num/den (bf16) directly.
// grid (bh=64, L/128=32).
// ---------------------------------------------------------------------------
__global__ __launch_bounds__(256) void numden_mfma(
    const ushort* __restrict__ QP, const ushort* __restrict__ KVSt,
    ushort* __restrict__ ATT)
{
    __shared__ __align__(16) ushort As[8192], Bs[8192];
    __shared__ float sden[128];
    const int bh = blockIdx.x, b = bh >> 4, h = bh & 15;
    const int l0 = blockIdx.y * 128;
    const ushort* Abase = QP + ((size_t)(b * L_ + l0) * H_ + h) * M_;
    const ushort* Bbase = KVSt + (size_t)bh * 16384;

    f32x4 acc[4][4];
    const f32x4 z4 = {0.f, 0.f, 0.f, 0.f};
    #pragma unroll
    for (int mt = 0; mt < 4; ++mt)
        #pragma unroll
        for (int nt = 0; nt < 4; ++nt) acc[mt][nt] = z4;

    mfma_gemm_g(Abase, Bbase, H_*M_, 128, 128, As, Bs, acc);

    const int t = threadIdx.x, w = t >> 6, lane = t & 63;
    const int wm = w >> 1, wn = w & 1, lr = lane & 15, rq = lane >> 4;

    if (wn == 1 && lr == 0) {       // col 64 = den
        #pragma unroll
        for (int mt = 0; mt < 4; ++mt)
            #pragma unroll
            for (int p = 0; p < 4; ++p)
                sden[wm*64 + mt*16 + rq*4 + p] = acc[mt][0][p];
    }
    __syncthreads();

    if (wn == 0) {
        #pragma unroll
        for (int mt = 0; mt < 4; ++mt) {
            #pragma unroll
            for (int p = 0; p < 4; ++p) {
                int row = wm*64 + mt*16 + rq*4 + p;
                float den = fmaxf(sden[row], 1e-10f);
                float rden = 1.0f / den;
                size_t gbase = (size_t)(b * L_ + l0 + row) * HID_ + h * DH_;
                #pragma unroll
                for (int nt = 0; nt < 4; ++nt)
                    ATT[gbase + nt*16 + lr] = f2b(acc[mt][nt][p] * rden);
            }
        }
    }
}

// ---------------------------------------------------------------------------
extern "C" void kernel_launch(void* const* d_in, const int* in_sizes, int n_in,
                              void* d_out, int out_size, void* d_ws, size_t ws_size,
                              hipStream_t stream)
{
    const float* Xq = (const float*)d_in[0];
    const float* Xs = (const float*)d_in[1];
    const float* Wq = (const float*)d_in[2];
    const float* Wk = (const float*)d_in[3];
    const float* Wv = (const float*)d_in[4];
    const float* Wo = (const float*)d_in[5];
    const float* Pj = (const float*)d_in[6];
    float* out = (float*)d_out;

    // Workspace layout (MB-aligned, audited disjoint per stage / safe alias):
    //   WqT..WoT [0,8)  Xqb [8,40)  Xsb [40,72)  QPb [72,136)
    //   KPb [136,200)   Vb [200,232)
    //   KPt  [8,72)    alias Xqb+Xsb  (dead after gemms)
    //   Vt   [136,168) alias KPb-lo   (KPb dead after kptrans)
    //   KVSP [168,184) alias KPb-mid
    //   KVSt [184,186) alias KPb-hi
    //   ksp  [0,1)     alias WqT      (dead after Q-gemm)
    //   ATT  [200,232) alias Vb       (dead after vtrans)
    char* ws = (char*)d_ws;
    ushort* WqT = (ushort*)(ws + 0);
    ushort* WkT = (ushort*)(ws + 2097152);
    ushort* WvT = (ushort*)(ws + 4194304);
    ushort* WoT = (ushort*)(ws + 6291456);
    ushort* Xqb = (ushort*)(ws + 8388608);
    ushort* Xsb = (ushort*)(ws + 41943040);
    ushort* QPb = (ushort*)(ws + 75497472);
    ushort* KPb = (ushort*)(ws + 142606336);
    ushort* Vb  = (ushort*)(ws + 209715200);
    ushort* KPt = (ushort*)(ws + 8388608);        // 64MB
    ushort* Vt  = (ushort*)(ws + 142606336);      // 32MB
    float*  KVSP = (float*)(ws + 176160768);      // 16MB
    ushort* KVSt = (ushort*)(ws + 192937984);     // 2MB
    float*  ksp  = (float*)(ws + 0);              // 1MB
    ushort* ATT  = Vb;

    dim3 tb(256);
    dim3 tb512(512);

    cvt_bf16<<<4096, tb, 0, stream>>>(Xq, Xqb, BL_*HID_/4);
    cvt_bf16<<<4096, tb, 0, stream>>>(Xs, Xsb, BL_*HID_/4);
    wtrans<<<dim3(16,16), tb, 0, stream>>>(Wq, WqT);
    wtrans<<<dim3(16,16), tb, 0, stream>>>(Wk, WkT);
    wtrans<<<dim3(16,16), tb, 0, stream>>>(Wv, WvT);
    wtrans<<<dim3(16,16), tb, 0, stream>>>(Wo, WoT);

    gemm_phi_mfma256<<<dim3(4, 64), tb512, 0, stream>>>(Xqb, WqT, Pj, QPb);
    gemm_phi_mfma256<<<dim3(4, 64), tb512, 0, stream>>>(Xsb, WkT, Pj, KPb);
    gemm256_bf16<<<dim3(4, 64), tb512, 0, stream>>>(Xsb, WvT, Vb);

    kptrans_kernel<<<dim3(64, 32), tb, 0, stream>>>(KPb, KPt, ksp);
    vtrans_kernel<<<dim3(64, 32), tb, 0, stream>>>(Vb, Vt);

    kvs_mfma<<<dim3(64, 8), tb, 0, stream>>>(Vt, KPt, KVSP);
    kvs_reduce_kernel<<<64, tb, 0, stream>>>(KVSP, ksp, KVSt);

    numden_mfma<<<dim3(B_*H_, L_/128), tb, 0, stream>>>(QPb, KVSt, ATT);

    gemm256_f32<<<dim3(4, 64), tb512, 0, stream>>>(ATT, WoT, out);
    (void)in_sizes; (void)n_in; (void)out_size; (void)ws_size;
}